// Round 1
// baseline (160.519 us; speedup 1.0000x reference)
//
#include <hip/hip_runtime.h>
#include <hip/hip_bf16.h>

typedef __bf16 bf16x8 __attribute__((ext_vector_type(8)));
typedef float  f32x4  __attribute__((ext_vector_type(4)));

#define DE_   64
#define DV_   64
#define DC_   32
#define DOUT_ 64
#define DIN_  224
#define NFRAG 28   // 7 k-steps * 4 n-tiles

// Pre-swizzle W ([224][64] f32 row-major) into bf16 MFMA B-fragment order:
// frag f = ks*4+nt ; lane holds B[k][col] with col = nt*16+(lane&15),
// k = ks*32 + (lane>>4)*8 + j, j=0..7 contiguous -> 16B per lane.
__global__ void prep_w_kernel(const float* __restrict__ W, __bf16* __restrict__ wf) {
    int f    = blockIdx.x;          // 0..27
    int lane = threadIdx.x;         // 0..63
    int ks = f >> 2, nt = f & 3;
    int col = nt * 16 + (lane & 15);
    int k0  = ks * 32 + (lane >> 4) * 8;
    bf16x8 v;
#pragma unroll
    for (int j = 0; j < 8; ++j)
        v[j] = (__bf16)W[(k0 + j) * DOUT_ + col];
    reinterpret_cast<bf16x8*>(wf)[f * 64 + lane] = v;
}

__global__ __launch_bounds__(256, 2)
void edge_mlp_kernel(const float* __restrict__ edata,
                     const float* __restrict__ vdata,
                     const float* __restrict__ cdata,
                     const int*   __restrict__ snd,
                     const int*   __restrict__ rcv,
                     const __bf16* __restrict__ wf,
                     const float* __restrict__ bias,
                     float* __restrict__ out,
                     int E, int NV, int n_tiles, int tiles_per_batch,
                     int total_waves) {
    const int lane = threadIdx.x & 63;
    const int wid  = blockIdx.x * (blockDim.x >> 6) + (threadIdx.x >> 6);
    const int lr   = lane & 15;   // A-row within tile / D-col within n-tile
    const int lg   = lane >> 4;   // k-group
    const int kl   = lg * 8;

    // Whole W stays in registers (28 frags * 4 VGPR = 112 VGPR).
    bf16x8 w[NFRAG];
#pragma unroll
    for (int f = 0; f < NFRAG; ++f)
        w[f] = reinterpret_cast<const bf16x8*>(wf)[f * 64 + lane];

    float bias_v[4];
#pragma unroll
    for (int nt = 0; nt < 4; ++nt) bias_v[nt] = bias[nt * 16 + lr];

    for (int tile = wid; tile < n_tiles; tile += total_waves) {
        const int  b   = (tile >= tiles_per_batch) ? 1 : 0;
        const long row = (long)tile * 16 + lr;     // this lane's A-row (global)
        const int  s   = snd[row];
        const int  r   = rcv[row];
        const float* vb = vdata + (long)b * NV * DV_;

        f32x4 acc[4];
#pragma unroll
        for (int nt = 0; nt < 4; ++nt) acc[nt] = f32x4{0.f, 0.f, 0.f, 0.f};

#pragma unroll
        for (int ks = 0; ks < 7; ++ks) {
            const float* p;
            if      (ks < 2) p = edata + row * DE_ + ks * 32 + kl;
            else if (ks < 4) p = vb + (long)s * DV_ + (ks - 2) * 32 + kl;
            else if (ks < 6) p = vb + (long)r * DV_ + (ks - 4) * 32 + kl;
            else             p = cdata + b * DC_ + kl;
            float4 f0 = *reinterpret_cast<const float4*>(p);
            float4 f1 = *reinterpret_cast<const float4*>(p + 4);
            bf16x8 a;
            a[0] = (__bf16)f0.x; a[1] = (__bf16)f0.y;
            a[2] = (__bf16)f0.z; a[3] = (__bf16)f0.w;
            a[4] = (__bf16)f1.x; a[5] = (__bf16)f1.y;
            a[6] = (__bf16)f1.z; a[7] = (__bf16)f1.w;
#pragma unroll
            for (int nt = 0; nt < 4; ++nt)
                acc[nt] = __builtin_amdgcn_mfma_f32_16x16x32_bf16(
                              a, w[ks * 4 + nt], acc[nt], 0, 0, 0);
        }

        // D layout (m89): col = lane&15 (+16*nt), row = (lane>>4)*4 + j
        const long rb = (long)tile * 16;
#pragma unroll
        for (int nt = 0; nt < 4; ++nt) {
#pragma unroll
            for (int j = 0; j < 4; ++j) {
                float v = acc[nt][j] + bias_v[nt];
                out[(rb + lg * 4 + j) * DOUT_ + nt * 16 + lr] = v > 0.f ? v : 0.f;
            }
        }
    }
}

extern "C" void kernel_launch(void* const* d_in, const int* in_sizes, int n_in,
                              void* d_out, int out_size, void* d_ws, size_t ws_size,
                              hipStream_t stream) {
    const float* edata = (const float*)d_in[0];
    const float* vdata = (const float*)d_in[1];
    const float* cdata = (const float*)d_in[2];
    const int*   snd   = (const int*)d_in[3];
    const int*   rcv   = (const int*)d_in[4];
    const float* W     = (const float*)d_in[5];
    const float* bias  = (const float*)d_in[6];
    float* out = (float*)d_out;

    const int Etot = in_sizes[3];            // B*E = 800000
    const int Bb   = in_sizes[2] / DC_;      // 2
    const int E    = Etot / Bb;              // 400000
    const int NV   = in_sizes[1] / (Bb * DV_); // 50000
    const int n_tiles = Etot / 16;           // 50000
    const int tiles_per_batch = E / 16;      // 25000

    __bf16* wf = (__bf16*)d_ws;              // 28 KB fragment buffer

    hipLaunchKernelGGL(prep_w_kernel, dim3(NFRAG), dim3(64), 0, stream, W, wf);

    const int blocks = 1024;
    const int total_waves = blocks * 4;
    hipLaunchKernelGGL(edge_mlp_kernel, dim3(blocks), dim3(256), 0, stream,
                       edata, vdata, cdata, snd, rcv, wf, bias, out,
                       E, NV, n_tiles, tiles_per_batch, total_waves);
}

// Round 2
// 135.054 us; speedup vs baseline: 1.1886x; 1.1886x over previous
//
#include <hip/hip_runtime.h>
#include <hip/hip_bf16.h>

typedef __bf16 bf16x8 __attribute__((ext_vector_type(8)));
typedef float  f32x4  __attribute__((ext_vector_type(4)));

#define DE_   64
#define DV_   64
#define DC_   32
#define DOUT_ 64
#define DIN_  224
#define NFRAG 28   // 7 k-steps * 4 n-tiles

// Pre-swizzle W ([224][64] f32 row-major) into bf16 MFMA B-fragment order:
// frag f = ks*4+nt ; lane holds B[k][col] with col = nt*16+(lane&15),
// k = ks*32 + (lane>>4)*8 + j, j=0..7 contiguous -> 16B per lane.
__global__ void prep_w_kernel(const float* __restrict__ W, __bf16* __restrict__ wf) {
    int f    = blockIdx.x;          // 0..27
    int lane = threadIdx.x;         // 0..63
    int ks = f >> 2, nt = f & 3;
    int col = nt * 16 + (lane & 15);
    int k0  = ks * 32 + (lane >> 4) * 8;
    bf16x8 v;
#pragma unroll
    for (int j = 0; j < 8; ++j)
        v[j] = (__bf16)W[(k0 + j) * DOUT_ + col];
    reinterpret_cast<bf16x8*>(wf)[f * 64 + lane] = v;
}

// One wave per 16-edge tile. 12500 blocks x 256 threads = 50000 waves.
__global__ __launch_bounds__(256, 6)
void edge_mlp_kernel(const float* __restrict__ edata,
                     const float* __restrict__ vdata,
                     const float* __restrict__ cdata,
                     const int*   __restrict__ snd,
                     const int*   __restrict__ rcv,
                     const __bf16* __restrict__ wf,
                     const float* __restrict__ bias,
                     float* __restrict__ out,
                     int NV, int n_tiles, int tiles_per_batch) {
    const int lane = threadIdx.x & 63;
    const int tile = blockIdx.x * (blockDim.x >> 6) + (threadIdx.x >> 6);
    if (tile >= n_tiles) return;

    const int lr = lane & 15;   // A-row within tile / D-col within n-tile
    const int lg = lane >> 4;   // k-group
    const int kl = lg * 8;

    const int  b   = (tile >= tiles_per_batch) ? 1 : 0;
    const long row = (long)tile * 16 + lr;     // this lane's A-row (global)
    // Start the dependent chain first:
    const int  s   = snd[row];
    const int  r   = rcv[row];
    const float* vb = vdata + (long)b * NV * DV_;

    // A operands: 7 k-steps x 2 float4 each, all independent loads.
    float4 f0[7], f1[7];
#pragma unroll
    for (int ks = 0; ks < 7; ++ks) {
        const float* p;
        if      (ks < 2) p = edata + row * DE_ + ks * 32 + kl;
        else if (ks < 4) p = vb + (long)s * DV_ + (ks - 2) * 32 + kl;
        else if (ks < 6) p = vb + (long)r * DV_ + (ks - 4) * 32 + kl;
        else             p = cdata + b * DC_ + kl;
        f0[ks] = *reinterpret_cast<const float4*>(p);
        f1[ks] = *reinterpret_cast<const float4*>(p + 4);
    }

    float bias_v[4];
#pragma unroll
    for (int nt = 0; nt < 4; ++nt) bias_v[nt] = bias[nt * 16 + lr];

    f32x4 acc[4];
#pragma unroll
    for (int nt = 0; nt < 4; ++nt) acc[nt] = f32x4{0.f, 0.f, 0.f, 0.f};

#pragma unroll
    for (int ks = 0; ks < 7; ++ks) {
        bf16x8 a;
        a[0] = (__bf16)f0[ks].x; a[1] = (__bf16)f0[ks].y;
        a[2] = (__bf16)f0[ks].z; a[3] = (__bf16)f0[ks].w;
        a[4] = (__bf16)f1[ks].x; a[5] = (__bf16)f1[ks].y;
        a[6] = (__bf16)f1[ks].z; a[7] = (__bf16)f1[ks].w;
#pragma unroll
        for (int nt = 0; nt < 4; ++nt) {
            bf16x8 w = reinterpret_cast<const bf16x8*>(wf)[(ks * 4 + nt) * 64 + lane];
            acc[nt] = __builtin_amdgcn_mfma_f32_16x16x32_bf16(a, w, acc[nt], 0, 0, 0);
        }
    }

    // D layout (m89): col = lane&15 (+16*nt), row = (lane>>4)*4 + j
    const long rb = (long)tile * 16;
#pragma unroll
    for (int nt = 0; nt < 4; ++nt) {
#pragma unroll
        for (int j = 0; j < 4; ++j) {
            float v = acc[nt][j] + bias_v[nt];
            v = v > 0.f ? v : 0.f;
            __builtin_nontemporal_store(v, &out[(rb + lg * 4 + j) * DOUT_ + nt * 16 + lr]);
        }
    }
}

extern "C" void kernel_launch(void* const* d_in, const int* in_sizes, int n_in,
                              void* d_out, int out_size, void* d_ws, size_t ws_size,
                              hipStream_t stream) {
    const float* edata = (const float*)d_in[0];
    const float* vdata = (const float*)d_in[1];
    const float* cdata = (const float*)d_in[2];
    const int*   snd   = (const int*)d_in[3];
    const int*   rcv   = (const int*)d_in[4];
    const float* W     = (const float*)d_in[5];
    const float* bias  = (const float*)d_in[6];
    float* out = (float*)d_out;

    const int Etot = in_sizes[3];              // B*E = 800000
    const int Bb   = in_sizes[2] / DC_;        // 2
    const int E    = Etot / Bb;                // 400000
    const int NV   = in_sizes[1] / (Bb * DV_); // 50000
    const int n_tiles = (Etot + 15) / 16;      // 50000
    const int tiles_per_batch = E / 16;        // 25000

    __bf16* wf = (__bf16*)d_ws;                // 28 KB fragment buffer

    hipLaunchKernelGGL(prep_w_kernel, dim3(NFRAG), dim3(64), 0, stream, W, wf);

    const int waves_per_block = 4;             // 256 threads
    const int blocks = (n_tiles + waves_per_block - 1) / waves_per_block;
    hipLaunchKernelGGL(edge_mlp_kernel, dim3(blocks), dim3(256), 0, stream,
                       edata, vdata, cdata, snd, rcv, wf, bias, out,
                       NV, n_tiles, tiles_per_batch);
}